// Round 23
// baseline (523.947 us; speedup 1.0000x reference)
//
#include <hip/hip_runtime.h>
#include <hip/hip_fp16.h>
#include <cstdint>

// 2-layer GAT, PyG GATConv semantics (concat heads, self-loops, segment softmax).
// R23: degree-sorted node permutation for the aggregation kernels. R22 evidence:
// agg1 (barrier before MFMA epilogue) runs at 1.73 TB/s effective fetch vs
// barrier-free agg2's ~2.9 TB/s => barrier-skew-bound (block waits for max
// in-degree of its 10 nodes, E[max10 Poisson(17)] ~ 27 vs mean 17 = 1.6x).
// Fix: counting-sort nodes by descending degree (128 buckets, 3 tiny kernels);
// agg1/agg2 process perm[slot] so each block gets equal-degree nodes.
// agg1 = R22 (gather + 5-wave MFMA x2@W2' epilogue, per-head-correct algebra);
// agg2 = proven per-head gather; gemm1 = R14 structure; CSR build = R7.
// Softmax max-subtraction omitted: shift-invariant, |e| <= ~10 so exp() safe in f32.

#define CH 4096
#define MAXB 512
#define SCAP 6144

using f16x8 = __attribute__((ext_vector_type(8))) _Float16;
using f32x4 = __attribute__((ext_vector_type(4))) float;

__device__ __forceinline__ float lrelu(float v) { return fmaxf(v, 0.2f * v); }

__global__ void ifill_kernel(int* __restrict__ p, int v, int n) {
  int i = blockIdx.x * blockDim.x + threadIdx.x;
  if (i < n) p[i] = v;
}

// Augmented W'^T [80][K] fp16: c<64: W[k][c]; 64..67: W_h@att_src_h;
// 68..71: W_h@att_dst_h; 72..79: 0. (W1 with K=256, W2 with K=64.)
__global__ void wprep2_kernel(const float* __restrict__ W,
                              const float* __restrict__ as,
                              const float* __restrict__ ad,
                              ushort* __restrict__ WT, int K) {
  int i = blockIdx.x * 256 + threadIdx.x;
  if (i >= 80 * K) return;
  int c = i / K, k = i % K;
  float v = 0.f;
  if (c < 64) {
    v = W[k * 64 + c];
  } else if (c < 68) {
    int hd = c - 64;
    for (int j = 0; j < 16; ++j) v += W[k * 64 + hd * 16 + j] * as[hd * 16 + j];
  } else if (c < 72) {
    int hd = c - 68;
    for (int j = 0; j < 16; ++j) v += W[k * 64 + hd * 16 + j] * ad[hd * 16 + j];
  }
  WT[c * K + k] = __half_as_ushort(__float2half_rn(v));
}

__global__ __launch_bounds__(256) void bucket_hist(const int* __restrict__ edst,
                                                   int E, int nbuck,
                                                   int* __restrict__ bucket_cnt) {
  __shared__ int hist[MAXB];
  const int t = threadIdx.x;
  for (int j = t; j < MAXB; j += 256) hist[j] = 0;
  __syncthreads();
  const int base = blockIdx.x * CH;
#pragma unroll
  for (int k = 0; k < CH / 256; ++k) {
    int e = base + k * 256 + t;
    if (e < E) atomicAdd(&hist[edst[e] >> 8], 1);
  }
  __syncthreads();
  for (int j = t; j < nbuck; j += 256) {
    int c = hist[j];
    if (c) atomicAdd(&bucket_cnt[j], c);
  }
}

__global__ __launch_bounds__(512) void bucket_scan(const int* __restrict__ bucket_cnt,
                                                   int* __restrict__ bucket_base,
                                                   int* __restrict__ bucket_cursor,
                                                   int nbuck) {
  __shared__ int part[512];
  const int t = threadIdx.x;
  int v = (t < nbuck) ? bucket_cnt[t] : 0;
  part[t] = v;
  __syncthreads();
  for (int off = 1; off < 512; off <<= 1) {
    int u = (t >= off) ? part[t - off] : 0;
    __syncthreads();
    part[t] += u;
    __syncthreads();
  }
  int ex = part[t] - v;
  if (t <= nbuck) {
    int w = (t < nbuck) ? ex : part[nbuck - 1];
    bucket_base[t] = w;
    if (t < nbuck) bucket_cursor[t] = w;
  }
}

__global__ __launch_bounds__(256) void place_kernel(const int* __restrict__ esrc,
                                                    const int* __restrict__ edst,
                                                    int E, int nbuck,
                                                    int* __restrict__ bucket_cursor,
                                                    unsigned int* __restrict__ pairs) {
  __shared__ int hist[MAXB];
  __shared__ int gbase[MAXB];
  __shared__ int rcnt[MAXB];
  const int t = threadIdx.x;
  for (int j = t; j < MAXB; j += 256) { hist[j] = 0; rcnt[j] = 0; }
  __syncthreads();
  const int base = blockIdx.x * CH;
  int b_[CH / 256];
  unsigned int p_[CH / 256];
#pragma unroll
  for (int k = 0; k < CH / 256; ++k) {
    int e = base + k * 256 + t;
    if (e < E) {
      int d = edst[e];
      int s = esrc[e];
      b_[k] = d >> 8;
      p_[k] = ((unsigned int)s << 8) | (unsigned int)(d & 255);
      atomicAdd(&hist[b_[k]], 1);
    } else {
      b_[k] = -1;
    }
  }
  __syncthreads();
  for (int j = t; j < nbuck; j += 256) {
    int c = hist[j];
    gbase[j] = c ? atomicAdd(&bucket_cursor[j], c) : 0;
  }
  __syncthreads();
#pragma unroll
  for (int k = 0; k < CH / 256; ++k) {
    if (b_[k] >= 0) {
      int r = atomicAdd(&rcnt[b_[k]], 1);
      pairs[gbase[b_[k]] + r] = p_[k];
    }
  }
}

__global__ __launch_bounds__(256) void bucket_build(
    const unsigned int* __restrict__ pairs, const int* __restrict__ bucket_base,
    int* __restrict__ ccol, int* __restrict__ start, int* __restrict__ endp,
    int n) {
  __shared__ int cnt[256];
  __shared__ int ls[256];
  __shared__ int csave[256];
  __shared__ int part[256];
  __shared__ int sorted[SCAP];
  const int t = threadIdx.x;
  const int b = blockIdx.x;
  const int d0 = b << 8;
  const int DR = min(256, n - d0);
  const int in_base = bucket_base[b];
  const int nloc = bucket_base[b + 1] - in_base;
  const int out_base = in_base + d0;

  cnt[t] = (t < DR) ? 1 : 0;
  __syncthreads();
  for (int i = t; i < nloc; i += 256)
    atomicAdd(&cnt[pairs[in_base + i] & 255u], 1);
  __syncthreads();
  int c = cnt[t];
  csave[t] = c;
  part[t] = c;
  __syncthreads();
#pragma unroll
  for (int off = 1; off < 256; off <<= 1) {
    int u = (t >= off) ? part[t - off] : 0;
    __syncthreads();
    part[t] += u;
    __syncthreads();
  }
  ls[t] = part[t] - c;
  __syncthreads();
  if (t < DR) {
    int s = out_base + ls[t];
    start[d0 + t] = s;
    endp[d0 + t] = s + csave[t];
    sorted[ls[t]] = d0 + t;
    cnt[t] = 1;
  }
  __syncthreads();
  for (int i = t; i < nloc; i += 256) {
    unsigned int p = pairs[in_base + i];
    int j = (int)(p & 255u);
    int r = atomicAdd(&cnt[j], 1);
    int pos = ls[j] + r;
    if (pos < SCAP) sorted[pos] = (int)(p >> 8);
  }
  __syncthreads();
  int tot = nloc + DR;
  if (tot > SCAP) tot = SCAP;
  for (int i = t; i < tot; i += 256) ccol[out_base + i] = sorted[i];
}

// ---- degree-sort (descending) of nodes: 128-bucket counting sort ----
__global__ __launch_bounds__(256) void deg_hist_kernel(
    const int* __restrict__ start, const int* __restrict__ endp, int n,
    int* __restrict__ dcnt) {
  __shared__ int h[128];
  if (threadIdx.x < 128) h[threadIdx.x] = 0;
  __syncthreads();
  int v = blockIdx.x * 256 + threadIdx.x;
  if (v < n) {
    int dg = endp[v] - start[v];
    if (dg > 127) dg = 127;
    atomicAdd(&h[127 - dg], 1);  // key = 127-deg -> descending by degree
  }
  __syncthreads();
  if (threadIdx.x < 128 && h[threadIdx.x])
    atomicAdd(&dcnt[threadIdx.x], h[threadIdx.x]);
}

__global__ __launch_bounds__(128) void deg_scan_kernel(const int* __restrict__ dcnt,
                                                       int* __restrict__ dcur) {
  __shared__ int part[128];
  const int t = threadIdx.x;
  int v = dcnt[t];
  part[t] = v;
  __syncthreads();
  for (int off = 1; off < 128; off <<= 1) {
    int u = (t >= off) ? part[t - off] : 0;
    __syncthreads();
    part[t] += u;
    __syncthreads();
  }
  dcur[t] = part[t] - v;  // exclusive
}

__global__ __launch_bounds__(256) void deg_place_kernel(
    const int* __restrict__ start, const int* __restrict__ endp, int n,
    int* __restrict__ dcur, int* __restrict__ perm) {
  int v = blockIdx.x * 256 + threadIdx.x;
  if (v < n) {
    int dg = endp[v] - start[v];
    if (dg > 127) dg = 127;
    int pos = atomicAdd(&dcur[127 - dg], 1);
    perm[pos] = v;
  }
}

// Layer-1 MFMA GEMM (R14, proven): h1[n][64] fp16 + as1/ad1 via fused att cols.
__global__ __launch_bounds__(256) void gemm1_mfma(
    const float* __restrict__ x, const ushort* __restrict__ wt,
    __half* __restrict__ h, float* __restrict__ as_, float* __restrict__ ad_,
    int n) {
  constexpr int K = 256, NS = K / 32;
  __shared__ _Float16 hs[64 * 88];
  __shared__ float att[64 * 12];
  const int tid = threadIdx.x;
  const int w = tid >> 6;
  const int lane = tid & 63;
  const int lr = lane & 15;
  const int kg = lane >> 4;
  const int row0 = blockIdx.x * 64;

  int rr = row0 + w * 16 + lr;
  if (rr > n - 1) rr = n - 1;

  const ushort* wbase = wt + lr * K + kg * 8;

  f16x8 af[NS];
  {
    float4 av[NS][2];
    const float* xp = x + (long long)rr * K + kg * 8;
#pragma unroll
    for (int s = 0; s < NS; ++s) {
      av[s][0] = *(const float4*)(xp + s * 32);
      av[s][1] = *(const float4*)(xp + s * 32 + 4);
    }
#pragma unroll
    for (int s = 0; s < NS; ++s) {
      af[s][0] = (_Float16)av[s][0].x; af[s][1] = (_Float16)av[s][0].y;
      af[s][2] = (_Float16)av[s][0].z; af[s][3] = (_Float16)av[s][0].w;
      af[s][4] = (_Float16)av[s][1].x; af[s][5] = (_Float16)av[s][1].y;
      af[s][6] = (_Float16)av[s][1].z; af[s][7] = (_Float16)av[s][1].w;
    }
  }

  f32x4 acc[5] = {};
#pragma unroll
  for (int s = 0; s < NS; ++s)
#pragma unroll
    for (int ct = 0; ct < 5; ++ct) {
      f16x8 b = *(const f16x8*)(wbase + ct * 16 * K + s * 32);
      acc[ct] = __builtin_amdgcn_mfma_f32_16x16x32_f16(af[s], b, acc[ct], 0, 0, 0);
    }

  const int orow = w * 16 + kg * 4;
#pragma unroll
  for (int ct = 0; ct < 4; ++ct)
#pragma unroll
    for (int r = 0; r < 4; ++r)
      hs[(orow + r) * 88 + ct * 16 + lr] = (_Float16)acc[ct][r];
  if (lr < 8) {
#pragma unroll
    for (int r = 0; r < 4; ++r)
      att[(orow + r) * 12 + lr] = acc[4][r];
  }
  __syncthreads();
#pragma unroll
  for (int j = 0; j < 2; ++j) {
    int s = tid + j * 256;
    int row = s >> 3, seg = s & 7;
    if (row0 + row < n)
      *(uint4*)(h + (long long)(row0 + row) * 64 + seg * 8) =
          *(const uint4*)&hs[row * 88 + seg * 8];
  }
  if (tid < 64) {
    if (row0 + tid < n)
      *(float4*)(as_ + (long long)(row0 + tid) * 4) = *(const float4*)&att[tid * 12];
  } else if (tid < 128) {
    int t2 = tid - 64;
    if (row0 + t2 < n)
      *(float4*)(ad_ + (long long)(row0 + t2) * 4) = *(const float4*)&att[t2 * 12 + 4];
  }
}

// agg1 + fused layer-2 linear via MFMA (R22), nodes taken from perm[] so each
// block's 10 nodes have ~equal degree (barrier-skew fix).
__global__ __launch_bounds__(320) void agg1_kernel(
    const int* __restrict__ ccol, const int* __restrict__ start,
    const int* __restrict__ endp, const int* __restrict__ perm,
    const float* __restrict__ as1, const float* __restrict__ ad1,
    const __half2* __restrict__ h2in, const float* __restrict__ bias,
    const ushort* __restrict__ wt2,
    __half* __restrict__ h2out, float* __restrict__ as2,
    float* __restrict__ ad2, int n) {
  __shared__ _Float16 x2s[16 * 72];  // x2 tile (10 rows used), stride 72
  __shared__ _Float16 hs2[16 * 72];  // h2 staging
  __shared__ float att2[16 * 12];    // as2/ad2 staging
  const int t = threadIdx.x;

  // Zero ONLY the pad region (rows 10-15; cols 64-71 of rows 0-9).
  for (int i = t; i < 6 * 72; i += 320) x2s[10 * 72 + i] = (_Float16)0.f;
  if (t < 80) x2s[(t >> 3) * 72 + 64 + (t & 7)] = (_Float16)0.f;

  const int lw = t >> 5;  // local node 0..9
  const int hl = t & 31;
  const int hh = hl >> 3;
  const int slot = blockIdx.x * 10 + lw;
  const bool act = slot < n;
  const int node = act ? perm[slot] : 0;

  const float adv = ad1[node * 4 + hh];
  const int s0i = start[node];
  const int d = act ? (endp[node] - s0i) : 0;
  const int* cp = ccol + s0i;
  float ax = 0.f, ay = 0.f, den = 0.f;
  int i = 0;
  for (; i + 4 <= d; i += 4) {
    int s0 = cp[i], s1 = cp[i + 1], s2 = cp[i + 2], s3 = cp[i + 3];
    float p0 = __expf(lrelu(as1[s0 * 4 + hh] + adv));
    float p1 = __expf(lrelu(as1[s1 * 4 + hh] + adv));
    float p2 = __expf(lrelu(as1[s2 * 4 + hh] + adv));
    float p3 = __expf(lrelu(as1[s3 * 4 + hh] + adv));
    float2 h0 = __half22float2(h2in[s0 * 32 + hl]);
    float2 h1 = __half22float2(h2in[s1 * 32 + hl]);
    float2 h2v = __half22float2(h2in[s2 * 32 + hl]);
    float2 h3 = __half22float2(h2in[s3 * 32 + hl]);
    den += (p0 + p1) + (p2 + p3);
    ax = fmaf(p0, h0.x, ax); ay = fmaf(p0, h0.y, ay);
    ax = fmaf(p1, h1.x, ax); ay = fmaf(p1, h1.y, ay);
    ax = fmaf(p2, h2v.x, ax); ay = fmaf(p2, h2v.y, ay);
    ax = fmaf(p3, h3.x, ax); ay = fmaf(p3, h3.y, ay);
  }
  for (; i < d; ++i) {
    int s0 = cp[i];
    float p0 = __expf(lrelu(as1[s0 * 4 + hh] + adv));
    float2 h0 = __half22float2(h2in[s0 * 32 + hl]);
    den += p0;
    ax = fmaf(p0, h0.x, ax); ay = fmaf(p0, h0.y, ay);
  }
  const float inv = 1.0f / (den + 1e-16f);
  float vx = act ? fmaxf(ax * inv + bias[hl * 2], 0.f) : 0.f;
  float vy = act ? fmaxf(ay * inv + bias[hl * 2 + 1], 0.f) : 0.f;
  x2s[lw * 72 + hl * 2] = (_Float16)vx;
  x2s[lw * 72 + hl * 2 + 1] = (_Float16)vy;
  __syncthreads();

  // MFMA: wave w computes D[:, w*16..w*16+15] of x2[16][64] @ W2'[64][80].
  {
    const int w = t >> 6;       // 0..4
    const int lane = t & 63;
    const int lr = lane & 15;
    const int kg = lane >> 4;
    const ushort* wb = wt2 + (w * 16 + lr) * 64 + kg * 8;
    f32x4 acc = {};
#pragma unroll
    for (int s = 0; s < 2; ++s) {
      f16x8 a = *(const f16x8*)&x2s[lr * 72 + s * 32 + kg * 8];
      f16x8 b = *(const f16x8*)(wb + s * 32);
      acc = __builtin_amdgcn_mfma_f32_16x16x32_f16(a, b, acc, 0, 0, 0);
    }
    if (w < 4) {
#pragma unroll
      for (int r = 0; r < 4; ++r)
        hs2[(kg * 4 + r) * 72 + w * 16 + lr] = (_Float16)acc[r];
    } else if (lr < 8) {
#pragma unroll
      for (int r = 0; r < 4; ++r)
        att2[(kg * 4 + r) * 12 + lr] = acc[r];
    }
  }
  __syncthreads();

  // Stores (rows scattered by perm; each row 128B contiguous).
  if (t < 80) {
    int row = t >> 3, seg = t & 7;
    int s2_ = blockIdx.x * 10 + row;
    if (s2_ < n) {
      int gn = perm[s2_];
      *(uint4*)(h2out + (long long)gn * 64 + seg * 8) =
          *(const uint4*)&hs2[row * 72 + seg * 8];
    }
  } else if (t < 90) {
    int row = t - 80;
    int s2_ = blockIdx.x * 10 + row;
    if (s2_ < n) {
      int gn = perm[s2_];
      *(float4*)(as2 + (long long)gn * 4) = *(const float4*)&att2[row * 12];
    }
  } else if (t < 100) {
    int row = t - 90;
    int s2_ = blockIdx.x * 10 + row;
    if (s2_ < n) {
      int gn = perm[s2_];
      *(float4*)(ad2 + (long long)gn * 4) = *(const float4*)&att2[row * 12 + 4];
    }
  }
}

// agg2 (proven form) with perm: gather h2 per head, normalize, + b2, f32 out.
__global__ __launch_bounds__(256) void agg2_kernel(
    const int* __restrict__ ccol, const int* __restrict__ start,
    const int* __restrict__ endp, const int* __restrict__ perm,
    const float* __restrict__ as2, const float* __restrict__ ad2,
    const __half2* __restrict__ h2, const float* __restrict__ bias,
    float* __restrict__ out, int n) {
  const int slot = blockIdx.x * 8 + (threadIdx.x >> 5);
  if (slot >= n) return;
  const int node = perm[slot];
  const int hl = threadIdx.x & 31;
  const int hh = hl >> 3;
  const float adv = ad2[node * 4 + hh];
  const int s0i = start[node];
  const int d = endp[node] - s0i;
  const int* cp = ccol + s0i;
  float ax = 0.f, ay = 0.f, den = 0.f;
  int i = 0;
  for (; i + 4 <= d; i += 4) {
    int s0 = cp[i], s1 = cp[i + 1], s2 = cp[i + 2], s3 = cp[i + 3];
    float p0 = __expf(lrelu(as2[s0 * 4 + hh] + adv));
    float p1 = __expf(lrelu(as2[s1 * 4 + hh] + adv));
    float p2 = __expf(lrelu(as2[s2 * 4 + hh] + adv));
    float p3 = __expf(lrelu(as2[s3 * 4 + hh] + adv));
    float2 h0 = __half22float2(h2[s0 * 32 + hl]);
    float2 h1 = __half22float2(h2[s1 * 32 + hl]);
    float2 h2v = __half22float2(h2[s2 * 32 + hl]);
    float2 h3 = __half22float2(h2[s3 * 32 + hl]);
    den += (p0 + p1) + (p2 + p3);
    ax = fmaf(p0, h0.x, ax); ay = fmaf(p0, h0.y, ay);
    ax = fmaf(p1, h1.x, ax); ay = fmaf(p1, h1.y, ay);
    ax = fmaf(p2, h2v.x, ax); ay = fmaf(p2, h2v.y, ay);
    ax = fmaf(p3, h3.x, ax); ay = fmaf(p3, h3.y, ay);
  }
  for (; i < d; ++i) {
    int s0 = cp[i];
    float p0 = __expf(lrelu(as2[s0 * 4 + hh] + adv));
    float2 h0 = __half22float2(h2[s0 * 32 + hl]);
    den += p0;
    ax = fmaf(p0, h0.x, ax); ay = fmaf(p0, h0.y, ay);
  }
  const float inv = 1.0f / (den + 1e-16f);
  float vx = ax * inv + bias[hl * 2];
  float vy = ay * inv + bias[hl * 2 + 1];
  *(float2*)(out + (long long)node * 64 + hl * 2) = make_float2(vx, vy);
}

extern "C" void kernel_launch(void* const* d_in, const int* in_sizes, int n_in,
                              void* d_out, int out_size, void* d_ws, size_t ws_size,
                              hipStream_t stream) {
  const float* x = (const float*)d_in[0];
  const int* ei = (const int*)d_in[1];
  const float* W1 = (const float*)d_in[2];
  const float* att_s1 = (const float*)d_in[3];
  const float* att_d1 = (const float*)d_in[4];
  const float* b1 = (const float*)d_in[5];
  const float* W2 = (const float*)d_in[6];
  const float* att_s2 = (const float*)d_in[7];
  const float* att_d2 = (const float*)d_in[8];
  const float* b2 = (const float*)d_in[9];

  const int n = in_sizes[0] / 256;  // 100000
  const int E = in_sizes[1] / 2;    // 1600000
  const int* esrc = ei;
  const int* edst = ei + E;
  const int nbuck = (n + 255) >> 8;  // 391

  float* wsf = (float*)d_ws;
  __half* hbuf = (__half*)wsf;                         // [n*64] fp16 h1 table
  __half* h2buf = (__half*)(wsf + (long long)n * 32);  // [n*64] fp16 h2 table
  float* as1 = wsf + (long long)n * 64;                // [n*4]
  float* ad1 = as1 + (long long)n * 4;
  float* as2 = ad1 + (long long)n * 4;
  float* ad2 = as2 + (long long)n * 4;
  int* bucket_cnt = (int*)(ad2 + (long long)n * 4);    // [MAXB]
  int* bucket_base = bucket_cnt + MAXB;                // [MAXB+1]
  int* bucket_cursor = bucket_base + MAXB + 1;         // [MAXB]
  int* start = bucket_cursor + MAXB;                   // [n]
  int* endp = start + n;                               // [n]
  unsigned int* pairs = (unsigned int*)(endp + n);     // [E]
  int* ccol = (int*)(pairs + E);                       // [E+n]
  ushort* wt1 = (ushort*)(((uintptr_t)(ccol + E + n) + 15) & ~(uintptr_t)15);  // [80*256]
  ushort* wt2 = wt1 + 80 * 256;                        // [80*64] augmented W2'
  int* dcnt = (int*)(wt2 + 80 * 64);                   // [128]
  int* dcur = dcnt + 128;                              // [128]
  int* perm = dcur + 128;                              // [n]
  float* out = (float*)d_out;

  const int ebk = (E + CH - 1) / CH;
  const int gb = (n + 63) / 64;
  const int nb1 = (n + 9) / 10;  // agg1: 10 nodes / 320-thread block
  const int nb2 = (n + 7) / 8;   // agg2: 8 nodes / 256-thread block
  const int vb = (n + 255) / 256;

  // ---- prep: augmented W'^T for both layers ----
  wprep2_kernel<<<(80 * 256 + 255) / 256, 256, 0, stream>>>(W1, att_s1, att_d1, wt1, 256);
  wprep2_kernel<<<(80 * 64 + 255) / 256, 256, 0, stream>>>(W2, att_s2, att_d2, wt2, 64);

  // ---- CSR bucket build ----
  ifill_kernel<<<(MAXB + 255) / 256, 256, 0, stream>>>(bucket_cnt, 0, MAXB);
  bucket_hist<<<ebk, 256, 0, stream>>>(edst, E, nbuck, bucket_cnt);
  bucket_scan<<<1, 512, 0, stream>>>(bucket_cnt, bucket_base, bucket_cursor, nbuck);
  place_kernel<<<ebk, 256, 0, stream>>>(esrc, edst, E, nbuck, bucket_cursor, pairs);
  bucket_build<<<nbuck, 256, 0, stream>>>(pairs, bucket_base, ccol, start, endp, n);

  // ---- degree-sorted node permutation (descending) ----
  ifill_kernel<<<1, 128, 0, stream>>>(dcnt, 0, 128);
  deg_hist_kernel<<<vb, 256, 0, stream>>>(start, endp, n, dcnt);
  deg_scan_kernel<<<1, 128, 0, stream>>>(dcnt, dcur);
  deg_place_kernel<<<vb, 256, 0, stream>>>(start, endp, n, dcur, perm);

  // ---- layer 1 GEMM + fused agg1/linear2 (MFMA epilogue) ----
  gemm1_mfma<<<gb, 256, 0, stream>>>(x, wt1, hbuf, as1, ad1, n);
  agg1_kernel<<<nb1, 320, 0, stream>>>(ccol, start, endp, perm, as1, ad1,
                                       (const __half2*)hbuf, b1, wt2,
                                       h2buf, as2, ad2, n);

  // ---- layer 2 aggregation ----
  agg2_kernel<<<nb2, 256, 0, stream>>>(ccol, start, endp, perm, as2, ad2,
                                       (const __half2*)h2buf, b2, out, n);
}

// Round 24
// 241.437 us; speedup vs baseline: 2.1701x; 2.1701x over previous
//
#include <hip/hip_runtime.h>
#include <hip/hip_fp16.h>
#include <cstdint>

// 2-layer GAT, PyG GATConv semantics (concat heads, self-loops, segment softmax).
// R24: deg_place fixed — R23's version did 100k atomicAdds on ~40 hot global
// counters (same-address serialization, 285us). Now: per-block LDS hist ->
// one block reservation per key -> per-node LDS rank (the pattern already
// proven in place_kernel). Everything else identical to R23 so the profile
// reveals whether degree-sorting fixed agg1's barrier skew (R22: 78us at
// 1.73 TB/s vs agg2's 2.9 TB/s).
// agg1 = R22 (gather + 5-wave MFMA x2@W2' epilogue); agg2 = proven gather;
// gemm1 = R14; CSR build = R7.
// Softmax max-subtraction omitted: shift-invariant, |e| <= ~10 so exp() safe in f32.

#define CH 4096
#define MAXB 512
#define SCAP 6144

using f16x8 = __attribute__((ext_vector_type(8))) _Float16;
using f32x4 = __attribute__((ext_vector_type(4))) float;

__device__ __forceinline__ float lrelu(float v) { return fmaxf(v, 0.2f * v); }

__global__ void ifill_kernel(int* __restrict__ p, int v, int n) {
  int i = blockIdx.x * blockDim.x + threadIdx.x;
  if (i < n) p[i] = v;
}

// Augmented W'^T [80][K] fp16: c<64: W[k][c]; 64..67: W_h@att_src_h;
// 68..71: W_h@att_dst_h; 72..79: 0. (W1 with K=256, W2 with K=64.)
__global__ void wprep2_kernel(const float* __restrict__ W,
                              const float* __restrict__ as,
                              const float* __restrict__ ad,
                              ushort* __restrict__ WT, int K) {
  int i = blockIdx.x * 256 + threadIdx.x;
  if (i >= 80 * K) return;
  int c = i / K, k = i % K;
  float v = 0.f;
  if (c < 64) {
    v = W[k * 64 + c];
  } else if (c < 68) {
    int hd = c - 64;
    for (int j = 0; j < 16; ++j) v += W[k * 64 + hd * 16 + j] * as[hd * 16 + j];
  } else if (c < 72) {
    int hd = c - 68;
    for (int j = 0; j < 16; ++j) v += W[k * 64 + hd * 16 + j] * ad[hd * 16 + j];
  }
  WT[c * K + k] = __half_as_ushort(__float2half_rn(v));
}

__global__ __launch_bounds__(256) void bucket_hist(const int* __restrict__ edst,
                                                   int E, int nbuck,
                                                   int* __restrict__ bucket_cnt) {
  __shared__ int hist[MAXB];
  const int t = threadIdx.x;
  for (int j = t; j < MAXB; j += 256) hist[j] = 0;
  __syncthreads();
  const int base = blockIdx.x * CH;
#pragma unroll
  for (int k = 0; k < CH / 256; ++k) {
    int e = base + k * 256 + t;
    if (e < E) atomicAdd(&hist[edst[e] >> 8], 1);
  }
  __syncthreads();
  for (int j = t; j < nbuck; j += 256) {
    int c = hist[j];
    if (c) atomicAdd(&bucket_cnt[j], c);
  }
}

__global__ __launch_bounds__(512) void bucket_scan(const int* __restrict__ bucket_cnt,
                                                   int* __restrict__ bucket_base,
                                                   int* __restrict__ bucket_cursor,
                                                   int nbuck) {
  __shared__ int part[512];
  const int t = threadIdx.x;
  int v = (t < nbuck) ? bucket_cnt[t] : 0;
  part[t] = v;
  __syncthreads();
  for (int off = 1; off < 512; off <<= 1) {
    int u = (t >= off) ? part[t - off] : 0;
    __syncthreads();
    part[t] += u;
    __syncthreads();
  }
  int ex = part[t] - v;
  if (t <= nbuck) {
    int w = (t < nbuck) ? ex : part[nbuck - 1];
    bucket_base[t] = w;
    if (t < nbuck) bucket_cursor[t] = w;
  }
}

__global__ __launch_bounds__(256) void place_kernel(const int* __restrict__ esrc,
                                                    const int* __restrict__ edst,
                                                    int E, int nbuck,
                                                    int* __restrict__ bucket_cursor,
                                                    unsigned int* __restrict__ pairs) {
  __shared__ int hist[MAXB];
  __shared__ int gbase[MAXB];
  __shared__ int rcnt[MAXB];
  const int t = threadIdx.x;
  for (int j = t; j < MAXB; j += 256) { hist[j] = 0; rcnt[j] = 0; }
  __syncthreads();
  const int base = blockIdx.x * CH;
  int b_[CH / 256];
  unsigned int p_[CH / 256];
#pragma unroll
  for (int k = 0; k < CH / 256; ++k) {
    int e = base + k * 256 + t;
    if (e < E) {
      int d = edst[e];
      int s = esrc[e];
      b_[k] = d >> 8;
      p_[k] = ((unsigned int)s << 8) | (unsigned int)(d & 255);
      atomicAdd(&hist[b_[k]], 1);
    } else {
      b_[k] = -1;
    }
  }
  __syncthreads();
  for (int j = t; j < nbuck; j += 256) {
    int c = hist[j];
    gbase[j] = c ? atomicAdd(&bucket_cursor[j], c) : 0;
  }
  __syncthreads();
#pragma unroll
  for (int k = 0; k < CH / 256; ++k) {
    if (b_[k] >= 0) {
      int r = atomicAdd(&rcnt[b_[k]], 1);
      pairs[gbase[b_[k]] + r] = p_[k];
    }
  }
}

__global__ __launch_bounds__(256) void bucket_build(
    const unsigned int* __restrict__ pairs, const int* __restrict__ bucket_base,
    int* __restrict__ ccol, int* __restrict__ start, int* __restrict__ endp,
    int n) {
  __shared__ int cnt[256];
  __shared__ int ls[256];
  __shared__ int csave[256];
  __shared__ int part[256];
  __shared__ int sorted[SCAP];
  const int t = threadIdx.x;
  const int b = blockIdx.x;
  const int d0 = b << 8;
  const int DR = min(256, n - d0);
  const int in_base = bucket_base[b];
  const int nloc = bucket_base[b + 1] - in_base;
  const int out_base = in_base + d0;

  cnt[t] = (t < DR) ? 1 : 0;
  __syncthreads();
  for (int i = t; i < nloc; i += 256)
    atomicAdd(&cnt[pairs[in_base + i] & 255u], 1);
  __syncthreads();
  int c = cnt[t];
  csave[t] = c;
  part[t] = c;
  __syncthreads();
#pragma unroll
  for (int off = 1; off < 256; off <<= 1) {
    int u = (t >= off) ? part[t - off] : 0;
    __syncthreads();
    part[t] += u;
    __syncthreads();
  }
  ls[t] = part[t] - c;
  __syncthreads();
  if (t < DR) {
    int s = out_base + ls[t];
    start[d0 + t] = s;
    endp[d0 + t] = s + csave[t];
    sorted[ls[t]] = d0 + t;
    cnt[t] = 1;
  }
  __syncthreads();
  for (int i = t; i < nloc; i += 256) {
    unsigned int p = pairs[in_base + i];
    int j = (int)(p & 255u);
    int r = atomicAdd(&cnt[j], 1);
    int pos = ls[j] + r;
    if (pos < SCAP) sorted[pos] = (int)(p >> 8);
  }
  __syncthreads();
  int tot = nloc + DR;
  if (tot > SCAP) tot = SCAP;
  for (int i = t; i < tot; i += 256) ccol[out_base + i] = sorted[i];
}

// ---- degree-sort (descending): hist + scan unchanged; place fixed ----
__global__ __launch_bounds__(256) void deg_hist_kernel(
    const int* __restrict__ start, const int* __restrict__ endp, int n,
    int* __restrict__ dcnt) {
  __shared__ int h[128];
  if (threadIdx.x < 128) h[threadIdx.x] = 0;
  __syncthreads();
  int v = blockIdx.x * 256 + threadIdx.x;
  if (v < n) {
    int dg = endp[v] - start[v];
    if (dg > 127) dg = 127;
    atomicAdd(&h[127 - dg], 1);  // key = 127-deg -> descending by degree
  }
  __syncthreads();
  if (threadIdx.x < 128 && h[threadIdx.x])
    atomicAdd(&dcnt[threadIdx.x], h[threadIdx.x]);
}

__global__ __launch_bounds__(128) void deg_scan_kernel(const int* __restrict__ dcnt,
                                                       int* __restrict__ dcur) {
  __shared__ int part[128];
  const int t = threadIdx.x;
  int v = dcnt[t];
  part[t] = v;
  __syncthreads();
  for (int off = 1; off < 128; off <<= 1) {
    int u = (t >= off) ? part[t - off] : 0;
    __syncthreads();
    part[t] += u;
    __syncthreads();
  }
  dcur[t] = part[t] - v;  // exclusive
}

// Fixed: per-block LDS hist -> one global reservation per (block,key) ->
// per-node LDS rank. (R23 version: 100k atomics on ~40 hot addrs = 285us.)
__global__ __launch_bounds__(256) void deg_place_kernel(
    const int* __restrict__ start, const int* __restrict__ endp, int n,
    int* __restrict__ dcur, int* __restrict__ perm) {
  __shared__ int h[128];
  __shared__ int gbase[128];
  __shared__ int rcnt[128];
  const int t = threadIdx.x;
  if (t < 128) { h[t] = 0; rcnt[t] = 0; }
  __syncthreads();
  int v = blockIdx.x * 256 + t;
  int key = -1;
  if (v < n) {
    int dg = endp[v] - start[v];
    if (dg > 127) dg = 127;
    key = 127 - dg;
    atomicAdd(&h[key], 1);
  }
  __syncthreads();
  if (t < 128) {
    int c = h[t];
    gbase[t] = c ? atomicAdd(&dcur[t], c) : 0;
  }
  __syncthreads();
  if (key >= 0) {
    int r = atomicAdd(&rcnt[key], 1);
    perm[gbase[key] + r] = v;
  }
}

// Layer-1 MFMA GEMM (R14, proven): h1[n][64] fp16 + as1/ad1 via fused att cols.
__global__ __launch_bounds__(256) void gemm1_mfma(
    const float* __restrict__ x, const ushort* __restrict__ wt,
    __half* __restrict__ h, float* __restrict__ as_, float* __restrict__ ad_,
    int n) {
  constexpr int K = 256, NS = K / 32;
  __shared__ _Float16 hs[64 * 88];
  __shared__ float att[64 * 12];
  const int tid = threadIdx.x;
  const int w = tid >> 6;
  const int lane = tid & 63;
  const int lr = lane & 15;
  const int kg = lane >> 4;
  const int row0 = blockIdx.x * 64;

  int rr = row0 + w * 16 + lr;
  if (rr > n - 1) rr = n - 1;

  const ushort* wbase = wt + lr * K + kg * 8;

  f16x8 af[NS];
  {
    float4 av[NS][2];
    const float* xp = x + (long long)rr * K + kg * 8;
#pragma unroll
    for (int s = 0; s < NS; ++s) {
      av[s][0] = *(const float4*)(xp + s * 32);
      av[s][1] = *(const float4*)(xp + s * 32 + 4);
    }
#pragma unroll
    for (int s = 0; s < NS; ++s) {
      af[s][0] = (_Float16)av[s][0].x; af[s][1] = (_Float16)av[s][0].y;
      af[s][2] = (_Float16)av[s][0].z; af[s][3] = (_Float16)av[s][0].w;
      af[s][4] = (_Float16)av[s][1].x; af[s][5] = (_Float16)av[s][1].y;
      af[s][6] = (_Float16)av[s][1].z; af[s][7] = (_Float16)av[s][1].w;
    }
  }

  f32x4 acc[5] = {};
#pragma unroll
  for (int s = 0; s < NS; ++s)
#pragma unroll
    for (int ct = 0; ct < 5; ++ct) {
      f16x8 b = *(const f16x8*)(wbase + ct * 16 * K + s * 32);
      acc[ct] = __builtin_amdgcn_mfma_f32_16x16x32_f16(af[s], b, acc[ct], 0, 0, 0);
    }

  const int orow = w * 16 + kg * 4;
#pragma unroll
  for (int ct = 0; ct < 4; ++ct)
#pragma unroll
    for (int r = 0; r < 4; ++r)
      hs[(orow + r) * 88 + ct * 16 + lr] = (_Float16)acc[ct][r];
  if (lr < 8) {
#pragma unroll
    for (int r = 0; r < 4; ++r)
      att[(orow + r) * 12 + lr] = acc[4][r];
  }
  __syncthreads();
#pragma unroll
  for (int j = 0; j < 2; ++j) {
    int s = tid + j * 256;
    int row = s >> 3, seg = s & 7;
    if (row0 + row < n)
      *(uint4*)(h + (long long)(row0 + row) * 64 + seg * 8) =
          *(const uint4*)&hs[row * 88 + seg * 8];
  }
  if (tid < 64) {
    if (row0 + tid < n)
      *(float4*)(as_ + (long long)(row0 + tid) * 4) = *(const float4*)&att[tid * 12];
  } else if (tid < 128) {
    int t2 = tid - 64;
    if (row0 + t2 < n)
      *(float4*)(ad_ + (long long)(row0 + t2) * 4) = *(const float4*)&att[t2 * 12 + 4];
  }
}

// agg1 + fused layer-2 linear via MFMA (R22), nodes taken from perm[] so each
// block's 10 nodes have ~equal degree (barrier-skew fix).
__global__ __launch_bounds__(320) void agg1_kernel(
    const int* __restrict__ ccol, const int* __restrict__ start,
    const int* __restrict__ endp, const int* __restrict__ perm,
    const float* __restrict__ as1, const float* __restrict__ ad1,
    const __half2* __restrict__ h2in, const float* __restrict__ bias,
    const ushort* __restrict__ wt2,
    __half* __restrict__ h2out, float* __restrict__ as2,
    float* __restrict__ ad2, int n) {
  __shared__ _Float16 x2s[16 * 72];  // x2 tile (10 rows used), stride 72
  __shared__ _Float16 hs2[16 * 72];  // h2 staging
  __shared__ float att2[16 * 12];    // as2/ad2 staging
  const int t = threadIdx.x;

  // Zero ONLY the pad region (rows 10-15; cols 64-71 of rows 0-9).
  for (int i = t; i < 6 * 72; i += 320) x2s[10 * 72 + i] = (_Float16)0.f;
  if (t < 80) x2s[(t >> 3) * 72 + 64 + (t & 7)] = (_Float16)0.f;

  const int lw = t >> 5;  // local node 0..9
  const int hl = t & 31;
  const int hh = hl >> 3;
  const int slot = blockIdx.x * 10 + lw;
  const bool act = slot < n;
  const int node = act ? perm[slot] : 0;

  const float adv = ad1[node * 4 + hh];
  const int s0i = start[node];
  const int d = act ? (endp[node] - s0i) : 0;
  const int* cp = ccol + s0i;
  float ax = 0.f, ay = 0.f, den = 0.f;
  int i = 0;
  for (; i + 4 <= d; i += 4) {
    int s0 = cp[i], s1 = cp[i + 1], s2 = cp[i + 2], s3 = cp[i + 3];
    float p0 = __expf(lrelu(as1[s0 * 4 + hh] + adv));
    float p1 = __expf(lrelu(as1[s1 * 4 + hh] + adv));
    float p2 = __expf(lrelu(as1[s2 * 4 + hh] + adv));
    float p3 = __expf(lrelu(as1[s3 * 4 + hh] + adv));
    float2 h0 = __half22float2(h2in[s0 * 32 + hl]);
    float2 h1 = __half22float2(h2in[s1 * 32 + hl]);
    float2 h2v = __half22float2(h2in[s2 * 32 + hl]);
    float2 h3 = __half22float2(h2in[s3 * 32 + hl]);
    den += (p0 + p1) + (p2 + p3);
    ax = fmaf(p0, h0.x, ax); ay = fmaf(p0, h0.y, ay);
    ax = fmaf(p1, h1.x, ax); ay = fmaf(p1, h1.y, ay);
    ax = fmaf(p2, h2v.x, ax); ay = fmaf(p2, h2v.y, ay);
    ax = fmaf(p3, h3.x, ax); ay = fmaf(p3, h3.y, ay);
  }
  for (; i < d; ++i) {
    int s0 = cp[i];
    float p0 = __expf(lrelu(as1[s0 * 4 + hh] + adv));
    float2 h0 = __half22float2(h2in[s0 * 32 + hl]);
    den += p0;
    ax = fmaf(p0, h0.x, ax); ay = fmaf(p0, h0.y, ay);
  }
  const float inv = 1.0f / (den + 1e-16f);
  float vx = act ? fmaxf(ax * inv + bias[hl * 2], 0.f) : 0.f;
  float vy = act ? fmaxf(ay * inv + bias[hl * 2 + 1], 0.f) : 0.f;
  x2s[lw * 72 + hl * 2] = (_Float16)vx;
  x2s[lw * 72 + hl * 2 + 1] = (_Float16)vy;
  __syncthreads();

  // MFMA: wave w computes D[:, w*16..w*16+15] of x2[16][64] @ W2'[64][80].
  {
    const int w = t >> 6;       // 0..4
    const int lane = t & 63;
    const int lr = lane & 15;
    const int kg = lane >> 4;
    const ushort* wb = wt2 + (w * 16 + lr) * 64 + kg * 8;
    f32x4 acc = {};
#pragma unroll
    for (int s = 0; s < 2; ++s) {
      f16x8 a = *(const f16x8*)&x2s[lr * 72 + s * 32 + kg * 8];
      f16x8 b = *(const f16x8*)(wb + s * 32);
      acc = __builtin_amdgcn_mfma_f32_16x16x32_f16(a, b, acc, 0, 0, 0);
    }
    if (w < 4) {
#pragma unroll
      for (int r = 0; r < 4; ++r)
        hs2[(kg * 4 + r) * 72 + w * 16 + lr] = (_Float16)acc[r];
    } else if (lr < 8) {
#pragma unroll
      for (int r = 0; r < 4; ++r)
        att2[(kg * 4 + r) * 12 + lr] = acc[r];
    }
  }
  __syncthreads();

  // Stores (rows scattered by perm; each row 128B contiguous).
  if (t < 80) {
    int row = t >> 3, seg = t & 7;
    int s2_ = blockIdx.x * 10 + row;
    if (s2_ < n) {
      int gn = perm[s2_];
      *(uint4*)(h2out + (long long)gn * 64 + seg * 8) =
          *(const uint4*)&hs2[row * 72 + seg * 8];
    }
  } else if (t < 90) {
    int row = t - 80;
    int s2_ = blockIdx.x * 10 + row;
    if (s2_ < n) {
      int gn = perm[s2_];
      *(float4*)(as2 + (long long)gn * 4) = *(const float4*)&att2[row * 12];
    }
  } else if (t < 100) {
    int row = t - 90;
    int s2_ = blockIdx.x * 10 + row;
    if (s2_ < n) {
      int gn = perm[s2_];
      *(float4*)(ad2 + (long long)gn * 4) = *(const float4*)&att2[row * 12 + 4];
    }
  }
}

// agg2 (proven form) with perm: gather h2 per head, normalize, + b2, f32 out.
__global__ __launch_bounds__(256) void agg2_kernel(
    const int* __restrict__ ccol, const int* __restrict__ start,
    const int* __restrict__ endp, const int* __restrict__ perm,
    const float* __restrict__ as2, const float* __restrict__ ad2,
    const __half2* __restrict__ h2, const float* __restrict__ bias,
    float* __restrict__ out, int n) {
  const int slot = blockIdx.x * 8 + (threadIdx.x >> 5);
  if (slot >= n) return;
  const int node = perm[slot];
  const int hl = threadIdx.x & 31;
  const int hh = hl >> 3;
  const float adv = ad2[node * 4 + hh];
  const int s0i = start[node];
  const int d = endp[node] - s0i;
  const int* cp = ccol + s0i;
  float ax = 0.f, ay = 0.f, den = 0.f;
  int i = 0;
  for (; i + 4 <= d; i += 4) {
    int s0 = cp[i], s1 = cp[i + 1], s2 = cp[i + 2], s3 = cp[i + 3];
    float p0 = __expf(lrelu(as2[s0 * 4 + hh] + adv));
    float p1 = __expf(lrelu(as2[s1 * 4 + hh] + adv));
    float p2 = __expf(lrelu(as2[s2 * 4 + hh] + adv));
    float p3 = __expf(lrelu(as2[s3 * 4 + hh] + adv));
    float2 h0 = __half22float2(h2[s0 * 32 + hl]);
    float2 h1 = __half22float2(h2[s1 * 32 + hl]);
    float2 h2v = __half22float2(h2[s2 * 32 + hl]);
    float2 h3 = __half22float2(h2[s3 * 32 + hl]);
    den += (p0 + p1) + (p2 + p3);
    ax = fmaf(p0, h0.x, ax); ay = fmaf(p0, h0.y, ay);
    ax = fmaf(p1, h1.x, ax); ay = fmaf(p1, h1.y, ay);
    ax = fmaf(p2, h2v.x, ax); ay = fmaf(p2, h2v.y, ay);
    ax = fmaf(p3, h3.x, ax); ay = fmaf(p3, h3.y, ay);
  }
  for (; i < d; ++i) {
    int s0 = cp[i];
    float p0 = __expf(lrelu(as2[s0 * 4 + hh] + adv));
    float2 h0 = __half22float2(h2[s0 * 32 + hl]);
    den += p0;
    ax = fmaf(p0, h0.x, ax); ay = fmaf(p0, h0.y, ay);
  }
  const float inv = 1.0f / (den + 1e-16f);
  float vx = ax * inv + bias[hl * 2];
  float vy = ay * inv + bias[hl * 2 + 1];
  *(float2*)(out + (long long)node * 64 + hl * 2) = make_float2(vx, vy);
}

extern "C" void kernel_launch(void* const* d_in, const int* in_sizes, int n_in,
                              void* d_out, int out_size, void* d_ws, size_t ws_size,
                              hipStream_t stream) {
  const float* x = (const float*)d_in[0];
  const int* ei = (const int*)d_in[1];
  const float* W1 = (const float*)d_in[2];
  const float* att_s1 = (const float*)d_in[3];
  const float* att_d1 = (const float*)d_in[4];
  const float* b1 = (const float*)d_in[5];
  const float* W2 = (const float*)d_in[6];
  const float* att_s2 = (const float*)d_in[7];
  const float* att_d2 = (const float*)d_in[8];
  const float* b2 = (const float*)d_in[9];

  const int n = in_sizes[0] / 256;  // 100000
  const int E = in_sizes[1] / 2;    // 1600000
  const int* esrc = ei;
  const int* edst = ei + E;
  const int nbuck = (n + 255) >> 8;  // 391

  float* wsf = (float*)d_ws;
  __half* hbuf = (__half*)wsf;                         // [n*64] fp16 h1 table
  __half* h2buf = (__half*)(wsf + (long long)n * 32);  // [n*64] fp16 h2 table
  float* as1 = wsf + (long long)n * 64;                // [n*4]
  float* ad1 = as1 + (long long)n * 4;
  float* as2 = ad1 + (long long)n * 4;
  float* ad2 = as2 + (long long)n * 4;
  int* bucket_cnt = (int*)(ad2 + (long long)n * 4);    // [MAXB]
  int* bucket_base = bucket_cnt + MAXB;                // [MAXB+1]
  int* bucket_cursor = bucket_base + MAXB + 1;         // [MAXB]
  int* start = bucket_cursor + MAXB;                   // [n]
  int* endp = start + n;                               // [n]
  unsigned int* pairs = (unsigned int*)(endp + n);     // [E]
  int* ccol = (int*)(pairs + E);                       // [E+n]
  ushort* wt1 = (ushort*)(((uintptr_t)(ccol + E + n) + 15) & ~(uintptr_t)15);  // [80*256]
  ushort* wt2 = wt1 + 80 * 256;                        // [80*64] augmented W2'
  int* dcnt = (int*)(wt2 + 80 * 64);                   // [128]
  int* dcur = dcnt + 128;                              // [128]
  int* perm = dcur + 128;                              // [n]
  float* out = (float*)d_out;

  const int ebk = (E + CH - 1) / CH;
  const int gb = (n + 63) / 64;
  const int nb1 = (n + 9) / 10;  // agg1: 10 nodes / 320-thread block
  const int nb2 = (n + 7) / 8;   // agg2: 8 nodes / 256-thread block
  const int vb = (n + 255) / 256;

  // ---- prep: augmented W'^T for both layers ----
  wprep2_kernel<<<(80 * 256 + 255) / 256, 256, 0, stream>>>(W1, att_s1, att_d1, wt1, 256);
  wprep2_kernel<<<(80 * 64 + 255) / 256, 256, 0, stream>>>(W2, att_s2, att_d2, wt2, 64);

  // ---- CSR bucket build ----
  ifill_kernel<<<(MAXB + 255) / 256, 256, 0, stream>>>(bucket_cnt, 0, MAXB);
  bucket_hist<<<ebk, 256, 0, stream>>>(edst, E, nbuck, bucket_cnt);
  bucket_scan<<<1, 512, 0, stream>>>(bucket_cnt, bucket_base, bucket_cursor, nbuck);
  place_kernel<<<ebk, 256, 0, stream>>>(esrc, edst, E, nbuck, bucket_cursor, pairs);
  bucket_build<<<nbuck, 256, 0, stream>>>(pairs, bucket_base, ccol, start, endp, n);

  // ---- degree-sorted node permutation (descending) ----
  ifill_kernel<<<1, 128, 0, stream>>>(dcnt, 0, 128);
  deg_hist_kernel<<<vb, 256, 0, stream>>>(start, endp, n, dcnt);
  deg_scan_kernel<<<1, 128, 0, stream>>>(dcnt, dcur);
  deg_place_kernel<<<vb, 256, 0, stream>>>(start, endp, n, dcur, perm);

  // ---- layer 1 GEMM + fused agg1/linear2 (MFMA epilogue) ----
  gemm1_mfma<<<gb, 256, 0, stream>>>(x, wt1, hbuf, as1, ad1, n);
  agg1_kernel<<<nb1, 320, 0, stream>>>(ccol, start, endp, perm, as1, ad1,
                                       (const __half2*)hbuf, b1, wt2,
                                       h2buf, as2, ad2, n);

  // ---- layer 2 aggregation ----
  agg2_kernel<<<nb2, 256, 0, stream>>>(ccol, start, endp, perm, as2, ad2,
                                       (const __half2*)h2buf, b2, out, n);
}